// Round 3
// baseline (138.210 us; speedup 1.0000x reference)
//
#include <hip/hip_runtime.h>

// 21-qubit batched (B=4) state-vector simulator, 6 full passes + reduce.
// State: 4 x 2^21 f32 in d_ws (32 MB). Qubit q <-> bit (20-q) of flat index.
// This round: persistent blocks (grid=256, 1/CU), 2 tiles/block, double-buffered
// LDS (bufA prefetch via global_load_lds || bufB sweep chain) to overlap the
// global read of tile k+1 with the LDS/VALU sweeps of tile k.
// Tiles: 2^14 amps (64 KB), 512 threads, 32 amps/thread, windows {l0,l1,m,m+1,m+2}.
// LDS float4 slots XOR-swizzled: phys = l4 ^ ((l4>>3)&7) (involution, bank-spread).

#define NQ 21
#define SW(a) ((a) ^ (((a) >> 3) & 7))
#define SHC(q) __shfl(cv, (q)), __shfl(sv, (q))

template<int Q>
__device__ __forceinline__ void ry32(float* v, float c, float s) {
#pragma unroll
  for (int k = 0; k < 16; ++k) {
    int l0 = ((k >> Q) << (Q + 1)) | (k & ((1 << Q) - 1));
    int l1 = l0 | (1 << Q);
    float a0 = v[l0], a1 = v[l1];
    v[l0] = c * a0 - s * a1;
    v[l1] = s * a0 + c * a1;
  }
}

template<int C, int T>
__device__ __forceinline__ void cnot32(float* v) {
  constexpr int lo = (C < T) ? C : T;
  constexpr int hi = (C < T) ? T : C;
#pragma unroll
  for (int k = 0; k < 8; ++k) {
    int i1 = ((k >> lo) << (lo + 1)) | (k & ((1 << lo) - 1));
    int i2 = ((i1 >> hi) << (hi + 1)) | (i1 & ((1 << hi) - 1));
    int a = i2 | (1 << C);   // control = 1, target = 0
    int b = a | (1 << T);
    float tmp = v[a]; v[a] = v[b]; v[b] = tmp;
  }
}

// async global(f4) -> LDS(f4), 16B per lane; LDS dest wave-uniform+lane*16 (linear)
__device__ __forceinline__ void gll16(const float4* g, float4* l) {
  __builtin_amdgcn_global_load_lds(
      (const __attribute__((address_space(1))) void*)(const void*)g,
      (__attribute__((address_space(3))) void*)(void*)l, 16, 0, 0);
}

// logical LDS float4 addresses per sweep (l4 = local_amp_index >> 2, 12 bits)
#define A1 (tid | (rr << 9))
#define A2 ((tid & 0x7F) | (rr << 7) | ((tid >> 7) << 10))
#define A3 ((tid & 0x1F) | (rr << 5) | ((tid >> 5) << 8))
#define A4 ((tid & 7) | (rr << 3) | ((tid >> 3) << 6))
#define A5 ((tid & 1) | (rr << 1) | ((tid >> 1) << 4))
#define A6 (rr | (tid << 3))
// H-pass local->global f4 map (local l0..l5=g0..g5, l6..l13=g13..g20)
#define GHT(l4, tt) (((l4) & 0xF) | ((tt) << 4) | (((l4) >> 4) << 11))
#define GH(l4) GHT(l4, t)

// ---------------- L pass: tile = bits 0..13, t = bits 14..20 ----------------
template<bool INIT>
__global__ __launch_bounds__(512, 2) void k_L(const float* __restrict__ x,
                                              const float* __restrict__ w,
                                              float* __restrict__ st) {
  __shared__ __align__(16) float sA[16384];
  __shared__ __align__(16) float sB[16384];
  float4* a4 = reinterpret_cast<float4*>(sA);
  float4* s4 = reinterpret_cast<float4*>(sB);
  const int tid = threadIdx.x, lane = tid & 63;
  const int b = blockIdx.x >> 6;
  const int t0 = (blockIdx.x << 1) & 127;
  float cv = 1.f, sv = 0.f;
  if (lane < NQ) sincosf(0.5f * w[lane], &sv, &cv);
  float cx = 1.f, sx = 0.f;
  if (INIT && lane < NQ) sincosf(0.5f * x[b * NQ + lane], &sx, &cx);
  float4* gb = reinterpret_cast<float4*>(st) + ((size_t)b << 19);
  float v[32];
  float4* v4 = reinterpret_cast<float4*>(v);

#pragma unroll
  for (int iter = 0; iter < 2; ++iter) {
    const int t = t0 + iter;
    float4* g4 = gb + ((size_t)t << 12);

    // ---- S1: window {0,1,11,12,13} ----
    if (INIT) {
      // product state after x-RYs, pre-imaged through layer-1 chain C(20,19)..C(14,13)
      float Qp = 1.f;
#pragma unroll
      for (int i = 0; i < 9; ++i) {            // tid bit i -> g(2+i) -> qubit 18-i
        float cq = __shfl(cx, 18 - i), sq = __shfl(sx, 18 - i);
        Qp *= ((tid >> i) & 1) ? sq : cq;
      }
      float hfac[2];
#pragma unroll
      for (int bb = 0; bb < 2; ++bb) {         // g13 = bb, h = g[13..20]
        int h = (t << 1) | bb;
        int h0 = h ^ (h >> 1);                 // pre-image of high chain
        float p = 1.f;
#pragma unroll
        for (int j = 0; j < 8; ++j) {          // h0 bit j -> g(13+j) -> qubit 7-j
          float cq = __shfl(cx, 7 - j), sq = __shfl(sx, 7 - j);
          p *= ((h0 >> j) & 1) ? sq : cq;
        }
        hfac[bb] = p;
      }
      float c20 = __shfl(cx, 20), s20 = __shfl(sx, 20);
      float c19 = __shfl(cx, 19), s19 = __shfl(sx, 19);
      float c9  = __shfl(cx, 9),  s9  = __shfl(sx, 9);
      float c8  = __shfl(cx, 8),  s8  = __shfl(sx, 8);
      float w0t[4], w1t[4];
#pragma unroll
      for (int i = 0; i < 4; ++i) {
        w0t[i] = ((i & 1) ? s20 : c20) * ((i & 2) ? s19 : c19);  // bits g0,g1
        w1t[i] = ((i & 1) ? s9  : c9 ) * ((i & 2) ? s8  : c8 );  // bits g11,g12
      }
#pragma unroll
      for (int r = 0; r < 32; ++r)
        v[r] = hfac[(r >> 4) & 1] * w1t[(r >> 2) & 3] * w0t[r & 3] * Qp;
    } else if (iter == 0) {
#pragma unroll
      for (int rr = 0; rr < 8; ++rr) v4[rr] = g4[A1];
    } else {
#pragma unroll
      for (int rr = 0; rr < 8; ++rr) v4[rr] = a4[A1];   // prefetched, linear
    }
    cnot32<4, 3>(v); cnot32<3, 2>(v);           // C(13,12) C(12,11)
    ry32<4>(v, SHC(7)); ry32<3>(v, SHC(8));     // RY b13(q7) b12(q8)
#pragma unroll
    for (int rr = 0; rr < 8; ++rr) s4[SW(A1)] = v4[rr];
    if (!INIT && iter == 0) {                   // async prefetch tile1 -> bufA
      const float4* gn = g4 + (1 << 12);
#pragma unroll
      for (int rr = 0; rr < 8; ++rr) { int l4 = tid | (rr << 9); gll16(gn + l4, a4 + l4); }
    }
    __syncthreads();

    // ---- S2: window {0,1,9,10,11} ----
#pragma unroll
    for (int rr = 0; rr < 8; ++rr) v4[rr] = s4[SW(A2)];
    cnot32<4, 3>(v); cnot32<3, 2>(v);           // C(11,10) C(10,9)
    ry32<4>(v, SHC(9)); ry32<3>(v, SHC(10));
#pragma unroll
    for (int rr = 0; rr < 8; ++rr) s4[SW(A2)] = v4[rr];
    __syncthreads();

    // ---- S3: window {0,1,7,8,9} ----
#pragma unroll
    for (int rr = 0; rr < 8; ++rr) v4[rr] = s4[SW(A3)];
    cnot32<4, 3>(v); cnot32<3, 2>(v);           // C(9,8) C(8,7)
    ry32<4>(v, SHC(11)); ry32<3>(v, SHC(12));
#pragma unroll
    for (int rr = 0; rr < 8; ++rr) s4[SW(A3)] = v4[rr];
    __syncthreads();

    // ---- S4: window {0,1,5,6,7} ----
#pragma unroll
    for (int rr = 0; rr < 8; ++rr) v4[rr] = s4[SW(A4)];
    cnot32<4, 3>(v); cnot32<3, 2>(v);           // C(7,6) C(6,5)
    ry32<4>(v, SHC(13)); ry32<3>(v, SHC(14));
#pragma unroll
    for (int rr = 0; rr < 8; ++rr) s4[SW(A4)] = v4[rr];
    __syncthreads();

    // ---- S5: window {0,1,3,4,5} ----
#pragma unroll
    for (int rr = 0; rr < 8; ++rr) v4[rr] = s4[SW(A5)];
    cnot32<4, 3>(v); cnot32<3, 2>(v);           // C(5,4) C(4,3)
    ry32<4>(v, SHC(15)); ry32<3>(v, SHC(16));
#pragma unroll
    for (int rr = 0; rr < 8; ++rr) s4[SW(A5)] = v4[rr];
    __syncthreads();

    // ---- S6: window {0,1,2,3,4}; store to global ----
#pragma unroll
    for (int rr = 0; rr < 8; ++rr) v4[rr] = s4[SW(A6)];
    cnot32<3, 2>(v); cnot32<2, 1>(v); cnot32<1, 0>(v);   // C(3,2) C(2,1) C(1,0)
    ry32<3>(v, SHC(17)); ry32<2>(v, SHC(18)); ry32<1>(v, SHC(19));
#pragma unroll
    for (int rr = 0; rr < 8; ++rr) g4[A6] = v4[rr];
    if (iter == 0) __syncthreads();   // drains prefetch + stores; bufB reusable
  }
}

// ---------------- H pass: tile = bits {0..5,13..20}, t = bits 6..12 ----------------
__global__ __launch_bounds__(512, 2) void k_H(const float* __restrict__ w,
                                              float* __restrict__ st) {
  __shared__ __align__(16) float sA[16384];
  __shared__ __align__(16) float sB[16384];
  float4* a4 = reinterpret_cast<float4*>(sA);
  float4* s4 = reinterpret_cast<float4*>(sB);
  const int tid = threadIdx.x, lane = tid & 63;
  const int b = blockIdx.x >> 6;
  const int t0 = (blockIdx.x << 1) & 127;
  float cv = 1.f, sv = 0.f;
  if (lane < NQ) sincosf(0.5f * w[lane], &sv, &cv);
  float4* gb = reinterpret_cast<float4*>(st) + ((size_t)b << 19);
  float v[32];
  float4* v4 = reinterpret_cast<float4*>(v);

#pragma unroll
  for (int iter = 0; iter < 2; ++iter) {
    const int t = t0 + iter;

    // ---- A: window {l0,l1,l11,l12,l13} ----
    if (iter == 0) {
#pragma unroll
      for (int rr = 0; rr < 8; ++rr) v4[rr] = gb[GH(A1)];
    } else {
#pragma unroll
      for (int rr = 0; rr < 8; ++rr) v4[rr] = a4[A1];   // prefetched, linear
    }
    cnot32<0, 4>(v);                            // wrap C(g0,g20)
    ry32<0>(v, SHC(20)); ry32<4>(v, SHC(0)); ry32<3>(v, SHC(1)); ry32<2>(v, SHC(2));
    cnot32<4, 3>(v); cnot32<3, 2>(v);           // next chain C(g20,g19) C(g19,g18)
#pragma unroll
    for (int rr = 0; rr < 8; ++rr) s4[SW(A1)] = v4[rr];
    if (iter == 0) {                            // gather-prefetch tile1 -> bufA linear
#pragma unroll
      for (int rr = 0; rr < 8; ++rr) {
        int l4 = tid | (rr << 9);
        gll16(gb + GHT(l4, t0 + 1), a4 + l4);
      }
    }
    __syncthreads();

    // ---- B: window {l0,l1,l9,l10,l11} ----
#pragma unroll
    for (int rr = 0; rr < 8; ++rr) v4[rr] = s4[SW(A2)];
    ry32<3>(v, SHC(3)); ry32<2>(v, SHC(4));
    cnot32<4, 3>(v); cnot32<3, 2>(v);           // C(g18,g17) C(g17,g16)
#pragma unroll
    for (int rr = 0; rr < 8; ++rr) s4[SW(A2)] = v4[rr];
    __syncthreads();

    // ---- C: window {l0,l1,l7,l8,l9} ----
#pragma unroll
    for (int rr = 0; rr < 8; ++rr) v4[rr] = s4[SW(A3)];
    ry32<3>(v, SHC(5)); ry32<2>(v, SHC(6));
    cnot32<4, 3>(v); cnot32<3, 2>(v);           // C(g16,g15) C(g15,g14)
#pragma unroll
    for (int rr = 0; rr < 8; ++rr) s4[SW(A3)] = v4[rr];
    __syncthreads();

    // ---- D: window {l0,l1,l5,l6,l7}; store to global ----
#pragma unroll
    for (int rr = 0; rr < 8; ++rr) v4[rr] = s4[SW(A4)];
    cnot32<4, 3>(v);                            // C(g14,g13)
#pragma unroll
    for (int rr = 0; rr < 8; ++rr) gb[GH(A4)] = v4[rr];
    if (iter == 0) __syncthreads();
  }
}

// ---------------- final H pass + measurement ----------------
__global__ __launch_bounds__(512, 2) void k_Hfin(const float* __restrict__ w,
                                                 const float* __restrict__ st,
                                                 float* __restrict__ partial) {
  __shared__ __align__(16) float sA[16384];
  __shared__ __align__(16) float sB[16384];
  float4* a4 = reinterpret_cast<float4*>(sA);
  float4* s4 = reinterpret_cast<float4*>(sB);
  float* s = sB;
  const int tid = threadIdx.x, lane = tid & 63;
  const int b = blockIdx.x >> 6;
  const int t0 = (blockIdx.x << 1) & 127;
  float cv = 1.f, sv = 0.f;
  if (lane < NQ) sincosf(0.5f * w[lane], &sv, &cv);
  const float4* gb = reinterpret_cast<const float4*>(st) + ((size_t)b << 19);
  float v[32];
  float4* v4 = reinterpret_cast<float4*>(v);

#pragma unroll
  for (int iter = 0; iter < 2; ++iter) {
    const int t = t0 + iter;

    // ---- A ----
    if (iter == 0) {
#pragma unroll
      for (int rr = 0; rr < 8; ++rr) v4[rr] = gb[GH(A1)];
    } else {
#pragma unroll
      for (int rr = 0; rr < 8; ++rr) v4[rr] = a4[A1];
    }
    cnot32<0, 4>(v);
    ry32<0>(v, SHC(20)); ry32<4>(v, SHC(0)); ry32<3>(v, SHC(1)); ry32<2>(v, SHC(2));
#pragma unroll
    for (int rr = 0; rr < 8; ++rr) s4[SW(A1)] = v4[rr];
    if (iter == 0) {
#pragma unroll
      for (int rr = 0; rr < 8; ++rr) {
        int l4 = tid | (rr << 9);
        gll16(gb + GHT(l4, t0 + 1), a4 + l4);
      }
    }
    __syncthreads();

    // ---- B ----
#pragma unroll
    for (int rr = 0; rr < 8; ++rr) v4[rr] = s4[SW(A2)];
    ry32<3>(v, SHC(3)); ry32<2>(v, SHC(4));
#pragma unroll
    for (int rr = 0; rr < 8; ++rr) s4[SW(A2)] = v4[rr];
    __syncthreads();

    // ---- C: window {l0,l1,l7,l8,l9} -> reg bits q20,q19,q6,q5,q4 ----
#pragma unroll
    for (int rr = 0; rr < 8; ++rr) v4[rr] = s4[SW(A3)];
    __syncthreads();   // all LDS reads done; sB reused for reduction below
    ry32<3>(v, SHC(5)); ry32<2>(v, SHC(6));

    float S = 0, aq20 = 0, aq19 = 0, aq6 = 0, aq5 = 0, aq4 = 0;
#pragma unroll
    for (int r = 0; r < 32; ++r) {
      float p = v[r] * v[r];
      S += p;
      aq20 += (r & 1)  ? -p : p;   // l0  = g0  -> q20
      aq19 += (r & 2)  ? -p : p;   // l1  = g1  -> q19
      aq6  += (r & 4)  ? -p : p;   // l7  = g14 -> q6
      aq5  += (r & 8)  ? -p : p;   // l8  = g15 -> q5
      aq4  += (r & 16) ? -p : p;   // l9  = g16 -> q4
    }
    float a21[21];
    a21[20] = aq20; a21[19] = aq19; a21[6] = aq6; a21[5] = aq5; a21[4] = aq4;
    a21[18] = (tid & 1)   ? -S : S;  // l2  = g2  -> q18
    a21[17] = (tid & 2)   ? -S : S;
    a21[16] = (tid & 4)   ? -S : S;
    a21[15] = (tid & 8)   ? -S : S;
    a21[7]  = (tid & 16)  ? -S : S;  // l6  = g13 -> q7
    a21[3]  = (tid & 32)  ? -S : S;  // l10 = g17 -> q3
    a21[2]  = (tid & 64)  ? -S : S;
    a21[1]  = (tid & 128) ? -S : S;
    a21[0]  = (tid & 256) ? -S : S;  // l13 = g20 -> q0
    a21[14] = (t & 1)  ? -S : S;     // g6  -> q14
    a21[13] = (t & 2)  ? -S : S;
    a21[12] = (t & 4)  ? -S : S;
    a21[11] = (t & 8)  ? -S : S;
    a21[10] = (t & 16) ? -S : S;
    a21[9]  = (t & 32) ? -S : S;
    a21[8]  = (t & 64) ? -S : S;     // g12 -> q8

    const int wv = tid >> 6;
#pragma unroll
    for (int q = 0; q < 21; ++q) {
      float val = a21[q];
      val += __shfl_down(val, 32);
      val += __shfl_down(val, 16);
      val += __shfl_down(val, 8);
      val += __shfl_down(val, 4);
      val += __shfl_down(val, 2);
      val += __shfl_down(val, 1);
      if (lane == 0) s[q * 8 + wv] = val;
    }
    __syncthreads();
    if (tid < NQ) {
      float sum = 0.f;
#pragma unroll
      for (int k = 0; k < 8; ++k) sum += s[tid * 8 + k];
      partial[((blockIdx.x << 1) + iter) * NQ + tid] = sum;
    }
    if (iter == 0) __syncthreads();  // reduction reads done before next S1 writes sB
  }
}

// ---------------- deterministic final reduction ----------------
__global__ void k_red(const float* __restrict__ partial, float* __restrict__ out) {
  int tid = threadIdx.x;
  if (tid < 84) {
    int b = tid / NQ, q = tid % NQ;
    float sum = 0.f;
    for (int k = 0; k < 128; ++k) sum += partial[(b * 128 + k) * NQ + q];
    out[tid] = sum;     // tid == b*21 + q
  }
}

extern "C" void kernel_launch(void* const* d_in, const int* in_sizes, int n_in,
                              void* d_out, int out_size, void* d_ws, size_t ws_size,
                              hipStream_t stream) {
  const float* x = (const float*)d_in[0];   // (4,21) f32
  const float* w = (const float*)d_in[1];   // (3,21) f32
  float* out = (float*)d_out;               // (4,21) f32
  float* st = (float*)d_ws;                 // 4 * 2^21 f32
  float* partial = st + ((size_t)4 << 21);  // 512*21 f32
  if (ws_size < ((size_t)4 << 21) * 4 + 512 * 21 * 4) return;

  dim3 grid(256), blk(512);
  k_L<true> <<<grid, blk, 0, stream>>>(x, w +  0, st);
  k_H       <<<grid, blk, 0, stream>>>(w +  0, st);
  k_L<false><<<grid, blk, 0, stream>>>(nullptr, w + 21, st);
  k_H       <<<grid, blk, 0, stream>>>(w + 21, st);
  k_L<false><<<grid, blk, 0, stream>>>(nullptr, w + 42, st);
  k_Hfin    <<<grid, blk, 0, stream>>>(w + 42, st, partial);
  k_red     <<<1, dim3(128), 0, stream>>>(partial, out);
}

// Round 4
// 115.490 us; speedup vs baseline: 1.1967x; 1.1967x over previous
//
#include <hip/hip_runtime.h>
#include <hip/hip_fp16.h>

// 21-qubit batched (B=4) state-vector simulator, 6 full passes + reduce.
// R4: R2 structure (512 blocks x 512 thr, 64KB f32 LDS tile, 4 waves/SIMD),
// but inter-pass state stored as fp16 (16 MB) -> global traffic halved.
// All global I/O in 4-amp (8B, uint2) granules == old float4 indices, so the
// R2 sweep windows are unchanged. Compute + LDS stay f32.
// Qubit q <-> bit (20-q) of flat index. Tiles: 2^14 amps, 32 amps/thread,
// windows {l0,l1,m,m+1,m+2}. LDS f4 slots XOR-swizzled: phys = l4 ^ ((l4>>3)&7).

#define NQ 21
#define SW(a) ((a) ^ (((a) >> 3) & 7))
#define SHC(q) __shfl(cv, (q)), __shfl(sv, (q))

template<int Q>
__device__ __forceinline__ void ry32(float* v, float c, float s) {
#pragma unroll
  for (int k = 0; k < 16; ++k) {
    int l0 = ((k >> Q) << (Q + 1)) | (k & ((1 << Q) - 1));
    int l1 = l0 | (1 << Q);
    float a0 = v[l0], a1 = v[l1];
    v[l0] = c * a0 - s * a1;
    v[l1] = s * a0 + c * a1;
  }
}

template<int C, int T>
__device__ __forceinline__ void cnot32(float* v) {
  constexpr int lo = (C < T) ? C : T;
  constexpr int hi = (C < T) ? T : C;
#pragma unroll
  for (int k = 0; k < 8; ++k) {
    int i1 = ((k >> lo) << (lo + 1)) | (k & ((1 << lo) - 1));
    int i2 = ((i1 >> hi) << (hi + 1)) | (i1 & ((1 << hi) - 1));
    int a = i2 | (1 << C);   // control = 1, target = 0
    int b = a | (1 << T);
    float tmp = v[a]; v[a] = v[b]; v[b] = tmp;
  }
}

// 4 amps (8B) fp16 <-> 4 f32 regs
__device__ __forceinline__ void ld4(const uint2* __restrict__ g, int idx, float* dst) {
  uint2 r = g[idx];
  __half2 h0 = *reinterpret_cast<__half2*>(&r.x);
  __half2 h1 = *reinterpret_cast<__half2*>(&r.y);
  float2 f0 = __half22float2(h0), f1 = __half22float2(h1);
  dst[0] = f0.x; dst[1] = f0.y; dst[2] = f1.x; dst[3] = f1.y;
}
__device__ __forceinline__ uint2 pk4(const float* src) {
  __half2 h0 = __floats2half2_rn(src[0], src[1]);
  __half2 h1 = __floats2half2_rn(src[2], src[3]);
  uint2 r;
  r.x = *reinterpret_cast<unsigned int*>(&h0);
  r.y = *reinterpret_cast<unsigned int*>(&h1);
  return r;
}

// logical LDS float4 addresses per sweep (l4 = local_amp_index >> 2, 12 bits)
#define A1 (tid | (rr << 9))
#define A2 ((tid & 0x7F) | (rr << 7) | ((tid >> 7) << 10))
#define A3 ((tid & 0x1F) | (rr << 5) | ((tid >> 5) << 8))
#define A4 ((tid & 7) | (rr << 3) | ((tid >> 3) << 6))
#define A5 ((tid & 1) | (rr << 1) | ((tid >> 1) << 4))
#define A6 (rr | (tid << 3))
// H-pass local->global 4-amp-granule map (local l0..l5=g0..g5, l6..l13=g13..g20)
#define GH(l4) (((l4) & 0xF) | (t << 4) | (((l4) >> 4) << 11))

// ---------------- L pass: tile = bits 0..13, t = bits 14..20 ----------------
template<bool INIT>
__global__ __launch_bounds__(512, 4) void k_L(const float* __restrict__ x,
                                              const float* __restrict__ w,
                                              unsigned long long stp) {
  __shared__ __align__(16) float s[16384];
  float4* s4 = reinterpret_cast<float4*>(s);
  const int tid = threadIdx.x, lane = tid & 63;
  const int b = blockIdx.x >> 7, t = blockIdx.x & 127;
  float cv = 1.f, sv = 0.f;
  if (lane < NQ) sincosf(0.5f * w[lane], &sv, &cv);
  uint2* g2 = reinterpret_cast<uint2*>(stp) + ((size_t)b << 19) + ((size_t)t << 12);
  float v[32];

  // ---- S1: window {0,1,11,12,13} ----
  if (INIT) {
    // product state after x-RYs, pre-imaged through layer-1 chain C(20,19)..C(14,13)
    float cx = 1.f, sx = 0.f;
    if (lane < NQ) sincosf(0.5f * x[b * NQ + lane], &sx, &cx);
    float Qp = 1.f;
#pragma unroll
    for (int i = 0; i < 9; ++i) {            // tid bit i -> g(2+i) -> qubit 18-i
      float cq = __shfl(cx, 18 - i), sq = __shfl(sx, 18 - i);
      Qp *= ((tid >> i) & 1) ? sq : cq;
    }
    float hfac[2];
#pragma unroll
    for (int bb = 0; bb < 2; ++bb) {         // g13 = bb, h = g[13..20]
      int h = (t << 1) | bb;
      int h0 = h ^ (h >> 1);                 // pre-image of high chain
      float p = 1.f;
#pragma unroll
      for (int j = 0; j < 8; ++j) {          // h0 bit j -> g(13+j) -> qubit 7-j
        float cq = __shfl(cx, 7 - j), sq = __shfl(sx, 7 - j);
        p *= ((h0 >> j) & 1) ? sq : cq;
      }
      hfac[bb] = p;
    }
    float c20 = __shfl(cx, 20), s20 = __shfl(sx, 20);
    float c19 = __shfl(cx, 19), s19 = __shfl(sx, 19);
    float c9  = __shfl(cx, 9),  s9  = __shfl(sx, 9);
    float c8  = __shfl(cx, 8),  s8  = __shfl(sx, 8);
    float w0t[4], w1t[4];
#pragma unroll
    for (int i = 0; i < 4; ++i) {
      w0t[i] = ((i & 1) ? s20 : c20) * ((i & 2) ? s19 : c19);  // bits g0,g1
      w1t[i] = ((i & 1) ? s9  : c9 ) * ((i & 2) ? s8  : c8 );  // bits g11,g12
    }
#pragma unroll
    for (int r = 0; r < 32; ++r)
      v[r] = hfac[(r >> 4) & 1] * w1t[(r >> 2) & 3] * w0t[r & 3] * Qp;
  } else {
#pragma unroll
    for (int rr = 0; rr < 8; ++rr) ld4(g2, A1, v + 4 * rr);
  }
  cnot32<4, 3>(v); cnot32<3, 2>(v);           // C(13,12) C(12,11)
  ry32<4>(v, SHC(7)); ry32<3>(v, SHC(8));     // RY b13(q7) b12(q8)
#pragma unroll
  for (int rr = 0; rr < 8; ++rr) s4[SW(A1)] = *reinterpret_cast<float4*>(v + 4 * rr);
  __syncthreads();

  // ---- S2: window {0,1,9,10,11} ----
#pragma unroll
  for (int rr = 0; rr < 8; ++rr) *reinterpret_cast<float4*>(v + 4 * rr) = s4[SW(A2)];
  cnot32<4, 3>(v); cnot32<3, 2>(v);           // C(11,10) C(10,9)
  ry32<4>(v, SHC(9)); ry32<3>(v, SHC(10));
#pragma unroll
  for (int rr = 0; rr < 8; ++rr) s4[SW(A2)] = *reinterpret_cast<float4*>(v + 4 * rr);
  __syncthreads();

  // ---- S3: window {0,1,7,8,9} ----
#pragma unroll
  for (int rr = 0; rr < 8; ++rr) *reinterpret_cast<float4*>(v + 4 * rr) = s4[SW(A3)];
  cnot32<4, 3>(v); cnot32<3, 2>(v);           // C(9,8) C(8,7)
  ry32<4>(v, SHC(11)); ry32<3>(v, SHC(12));
#pragma unroll
  for (int rr = 0; rr < 8; ++rr) s4[SW(A3)] = *reinterpret_cast<float4*>(v + 4 * rr);
  __syncthreads();

  // ---- S4: window {0,1,5,6,7} ----
#pragma unroll
  for (int rr = 0; rr < 8; ++rr) *reinterpret_cast<float4*>(v + 4 * rr) = s4[SW(A4)];
  cnot32<4, 3>(v); cnot32<3, 2>(v);           // C(7,6) C(6,5)
  ry32<4>(v, SHC(13)); ry32<3>(v, SHC(14));
#pragma unroll
  for (int rr = 0; rr < 8; ++rr) s4[SW(A4)] = *reinterpret_cast<float4*>(v + 4 * rr);
  __syncthreads();

  // ---- S5: window {0,1,3,4,5} ----
#pragma unroll
  for (int rr = 0; rr < 8; ++rr) *reinterpret_cast<float4*>(v + 4 * rr) = s4[SW(A5)];
  cnot32<4, 3>(v); cnot32<3, 2>(v);           // C(5,4) C(4,3)
  ry32<4>(v, SHC(15)); ry32<3>(v, SHC(16));
#pragma unroll
  for (int rr = 0; rr < 8; ++rr) s4[SW(A5)] = *reinterpret_cast<float4*>(v + 4 * rr);
  __syncthreads();

  // ---- S6: window {0,1,2,3,4}; store to global (fp16) ----
#pragma unroll
  for (int rr = 0; rr < 8; ++rr) *reinterpret_cast<float4*>(v + 4 * rr) = s4[SW(A6)];
  cnot32<3, 2>(v); cnot32<2, 1>(v); cnot32<1, 0>(v);   // C(3,2) C(2,1) C(1,0)
  ry32<3>(v, SHC(17)); ry32<2>(v, SHC(18)); ry32<1>(v, SHC(19));
  {
    uint4* g4o = reinterpret_cast<uint4*>(g2);
#pragma unroll
    for (int rr = 0; rr < 8; rr += 2) {
      uint2 lo = pk4(v + 4 * rr), hi = pk4(v + 4 * rr + 4);
      uint4 o; o.x = lo.x; o.y = lo.y; o.z = hi.x; o.w = hi.y;
      g4o[((rr | (tid << 3)) >> 1)] = o;     // A6 pairs are adjacent
    }
  }
}

// ---------------- H pass: tile = bits {0..5,13..20}, t = bits 6..12 ----------------
__global__ __launch_bounds__(512, 4) void k_H(const float* __restrict__ w,
                                              unsigned long long stp) {
  __shared__ __align__(16) float s[16384];
  float4* s4 = reinterpret_cast<float4*>(s);
  const int tid = threadIdx.x, lane = tid & 63;
  const int b = blockIdx.x >> 7, t = blockIdx.x & 127;
  float cv = 1.f, sv = 0.f;
  if (lane < NQ) sincosf(0.5f * w[lane], &sv, &cv);
  uint2* gb = reinterpret_cast<uint2*>(stp) + ((size_t)b << 19);
  float v[32];

  // ---- A: window {l0,l1,l11,l12,l13} ----
#pragma unroll
  for (int rr = 0; rr < 8; ++rr) ld4(gb, GH(A1), v + 4 * rr);
  cnot32<0, 4>(v);                            // wrap C(g0,g20)
  ry32<0>(v, SHC(20)); ry32<4>(v, SHC(0)); ry32<3>(v, SHC(1)); ry32<2>(v, SHC(2));
  cnot32<4, 3>(v); cnot32<3, 2>(v);           // next chain C(g20,g19) C(g19,g18)
#pragma unroll
  for (int rr = 0; rr < 8; ++rr) s4[SW(A1)] = *reinterpret_cast<float4*>(v + 4 * rr);
  __syncthreads();

  // ---- B: window {l0,l1,l9,l10,l11} ----
#pragma unroll
  for (int rr = 0; rr < 8; ++rr) *reinterpret_cast<float4*>(v + 4 * rr) = s4[SW(A2)];
  ry32<3>(v, SHC(3)); ry32<2>(v, SHC(4));
  cnot32<4, 3>(v); cnot32<3, 2>(v);           // C(g18,g17) C(g17,g16)
#pragma unroll
  for (int rr = 0; rr < 8; ++rr) s4[SW(A2)] = *reinterpret_cast<float4*>(v + 4 * rr);
  __syncthreads();

  // ---- C: window {l0,l1,l7,l8,l9} ----
#pragma unroll
  for (int rr = 0; rr < 8; ++rr) *reinterpret_cast<float4*>(v + 4 * rr) = s4[SW(A3)];
  ry32<3>(v, SHC(5)); ry32<2>(v, SHC(6));
  cnot32<4, 3>(v); cnot32<3, 2>(v);           // C(g16,g15) C(g15,g14)
#pragma unroll
  for (int rr = 0; rr < 8; ++rr) s4[SW(A3)] = *reinterpret_cast<float4*>(v + 4 * rr);
  __syncthreads();

  // ---- D: window {l0,l1,l5,l6,l7}; store to global (fp16) ----
#pragma unroll
  for (int rr = 0; rr < 8; ++rr) *reinterpret_cast<float4*>(v + 4 * rr) = s4[SW(A4)];
  cnot32<4, 3>(v);                            // C(g14,g13)
#pragma unroll
  for (int rr = 0; rr < 8; ++rr) gb[GH(A4)] = pk4(v + 4 * rr);
}

// ---------------- final H pass + measurement ----------------
__global__ __launch_bounds__(512, 4) void k_Hfin(const float* __restrict__ w,
                                                 unsigned long long stp,
                                                 float* __restrict__ partial) {
  __shared__ __align__(16) float s[16384];
  float4* s4 = reinterpret_cast<float4*>(s);
  const int tid = threadIdx.x, lane = tid & 63;
  const int b = blockIdx.x >> 7, t = blockIdx.x & 127;
  float cv = 1.f, sv = 0.f;
  if (lane < NQ) sincosf(0.5f * w[lane], &sv, &cv);
  const uint2* gb = reinterpret_cast<const uint2*>(stp) + ((size_t)b << 19);
  float v[32];

  // ---- A ----
#pragma unroll
  for (int rr = 0; rr < 8; ++rr) ld4(gb, GH(A1), v + 4 * rr);
  cnot32<0, 4>(v);
  ry32<0>(v, SHC(20)); ry32<4>(v, SHC(0)); ry32<3>(v, SHC(1)); ry32<2>(v, SHC(2));
#pragma unroll
  for (int rr = 0; rr < 8; ++rr) s4[SW(A1)] = *reinterpret_cast<float4*>(v + 4 * rr);
  __syncthreads();

  // ---- B ----
#pragma unroll
  for (int rr = 0; rr < 8; ++rr) *reinterpret_cast<float4*>(v + 4 * rr) = s4[SW(A2)];
  ry32<3>(v, SHC(3)); ry32<2>(v, SHC(4));
#pragma unroll
  for (int rr = 0; rr < 8; ++rr) s4[SW(A2)] = *reinterpret_cast<float4*>(v + 4 * rr);
  __syncthreads();

  // ---- C: window {l0,l1,l7,l8,l9} -> reg bits q20,q19,q6,q5,q4 ----
#pragma unroll
  for (int rr = 0; rr < 8; ++rr) *reinterpret_cast<float4*>(v + 4 * rr) = s4[SW(A3)];
  __syncthreads();   // all LDS reads done; s reused for reduction below
  ry32<3>(v, SHC(5)); ry32<2>(v, SHC(6));

  float S = 0, aq20 = 0, aq19 = 0, aq6 = 0, aq5 = 0, aq4 = 0;
#pragma unroll
  for (int r = 0; r < 32; ++r) {
    float p = v[r] * v[r];
    S += p;
    aq20 += (r & 1)  ? -p : p;   // l0  = g0  -> q20
    aq19 += (r & 2)  ? -p : p;   // l1  = g1  -> q19
    aq6  += (r & 4)  ? -p : p;   // l7  = g14 -> q6
    aq5  += (r & 8)  ? -p : p;   // l8  = g15 -> q5
    aq4  += (r & 16) ? -p : p;   // l9  = g16 -> q4
  }
  float a21[21];
  a21[20] = aq20; a21[19] = aq19; a21[6] = aq6; a21[5] = aq5; a21[4] = aq4;
  a21[18] = (tid & 1)   ? -S : S;  // l2  = g2  -> q18
  a21[17] = (tid & 2)   ? -S : S;
  a21[16] = (tid & 4)   ? -S : S;
  a21[15] = (tid & 8)   ? -S : S;
  a21[7]  = (tid & 16)  ? -S : S;  // l6  = g13 -> q7
  a21[3]  = (tid & 32)  ? -S : S;  // l10 = g17 -> q3
  a21[2]  = (tid & 64)  ? -S : S;
  a21[1]  = (tid & 128) ? -S : S;
  a21[0]  = (tid & 256) ? -S : S;  // l13 = g20 -> q0
  a21[14] = (t & 1)  ? -S : S;     // g6  -> q14
  a21[13] = (t & 2)  ? -S : S;
  a21[12] = (t & 4)  ? -S : S;
  a21[11] = (t & 8)  ? -S : S;
  a21[10] = (t & 16) ? -S : S;
  a21[9]  = (t & 32) ? -S : S;
  a21[8]  = (t & 64) ? -S : S;     // g12 -> q8

  const int wv = tid >> 6;
#pragma unroll
  for (int q = 0; q < 21; ++q) {
    float val = a21[q];
    val += __shfl_down(val, 32);
    val += __shfl_down(val, 16);
    val += __shfl_down(val, 8);
    val += __shfl_down(val, 4);
    val += __shfl_down(val, 2);
    val += __shfl_down(val, 1);
    if (lane == 0) s[q * 8 + wv] = val;
  }
  __syncthreads();
  if (tid < NQ) {
    float sum = 0.f;
#pragma unroll
    for (int k = 0; k < 8; ++k) sum += s[tid * 8 + k];
    partial[blockIdx.x * NQ + tid] = sum;
  }
}

// ---------------- deterministic final reduction ----------------
__global__ void k_red(const float* __restrict__ partial, float* __restrict__ out) {
  int tid = threadIdx.x;
  if (tid < 84) {
    int b = tid / NQ, q = tid % NQ;
    float sum = 0.f;
    for (int k = 0; k < 128; ++k) sum += partial[(b * 128 + k) * NQ + q];
    out[tid] = sum;     // tid == b*21 + q
  }
}

extern "C" void kernel_launch(void* const* d_in, const int* in_sizes, int n_in,
                              void* d_out, int out_size, void* d_ws, size_t ws_size,
                              hipStream_t stream) {
  const float* x = (const float*)d_in[0];   // (4,21) f32
  const float* w = (const float*)d_in[1];   // (3,21) f32
  float* out = (float*)d_out;               // (4,21) f32
  unsigned long long stp = (unsigned long long)d_ws;            // 4*2^21 fp16 = 16 MB
  float* partial = (float*)((char*)d_ws + (((size_t)4 << 21) * 2));  // 512*21 f32
  if (ws_size < ((size_t)4 << 21) * 2 + 512 * NQ * 4) return;

  dim3 grid(512), blk(512);
  k_L<true> <<<grid, blk, 0, stream>>>(x, w +  0, stp);
  k_H       <<<grid, blk, 0, stream>>>(w +  0, stp);
  k_L<false><<<grid, blk, 0, stream>>>(nullptr, w + 21, stp);
  k_H       <<<grid, blk, 0, stream>>>(w + 21, stp);
  k_L<false><<<grid, blk, 0, stream>>>(nullptr, w + 42, stp);
  k_Hfin    <<<grid, blk, 0, stream>>>(w + 42, stp, partial);
  k_red     <<<1, dim3(128), 0, stream>>>(partial, out);
}

// Round 5
// 110.843 us; speedup vs baseline: 1.2469x; 1.0419x over previous
//
#include <hip/hip_runtime.h>
#include <hip/hip_fp16.h>

// 21-qubit batched (B=4) state-vector simulator, 6 full passes + reduce.
// R5: consecutive-bit windows via per-round-trip LDS bit-permutation layouts.
// Reads stay ds_read_b128 (slot bits 0,1 = window bits); writes are 32x b32
// scatter at compile-time XOR offsets (layout maps are GF(2)-linear).
// L = 4 sweeps (was 6), H = 3 (was 4), Hfin = 2 (was 3). fp16 global state.
// Qubit q <-> bit (20-q) of flat index. Tiles 2^14 amps, 512 thr, 32 amps/thr.
// Bank swizzle PH2: blk ^= ((blk>>3)&7) ^ ((blk>>6)&7) on f4-granule index.

#define NQ 21
#define SHC(q) __shfl(cv, (q)), __shfl(sv, (q))

__device__ constexpr int PH2(int slot) {
  int blk = slot >> 2;
  blk ^= ((blk >> 3) & 7) ^ ((blk >> 6) & 7);
  return (blk << 2) | (slot & 3);
}

template<int Q>
__device__ __forceinline__ void ry32(float* v, float c, float s) {
#pragma unroll
  for (int k = 0; k < 16; ++k) {
    int l0 = ((k >> Q) << (Q + 1)) | (k & ((1 << Q) - 1));
    int l1 = l0 | (1 << Q);
    float a0 = v[l0], a1 = v[l1];
    v[l0] = c * a0 - s * a1;
    v[l1] = s * a0 + c * a1;
  }
}

template<int C, int T>
__device__ __forceinline__ void cnot32(float* v) {
  constexpr int lo = (C < T) ? C : T;
  constexpr int hi = (C < T) ? T : C;
#pragma unroll
  for (int k = 0; k < 8; ++k) {
    int i1 = ((k >> lo) << (lo + 1)) | (k & ((1 << lo) - 1));
    int i2 = ((i1 >> hi) << (hi + 1)) | (i1 & ((1 << hi) - 1));
    int a = i2 | (1 << C);   // control = 1, target = 0
    int b = a | (1 << T);
    float tmp = v[a]; v[a] = v[b]; v[b] = tmp;
  }
}

// 4 amps (8B) fp16 <-> 4 f32 regs
__device__ __forceinline__ void ld4(const uint2* __restrict__ g, int idx, float* dst) {
  uint2 r = g[idx];
  __half2 h0 = *reinterpret_cast<__half2*>(&r.x);
  __half2 h1 = *reinterpret_cast<__half2*>(&r.y);
  float2 f0 = __half22float2(h0), f1 = __half22float2(h1);
  dst[0] = f0.x; dst[1] = f0.y; dst[2] = f1.x; dst[3] = f1.y;
}
__device__ __forceinline__ uint2 pk4(const float* src) {
  __half2 h0 = __floats2half2_rn(src[0], src[1]);
  __half2 h1 = __floats2half2_rn(src[2], src[3]);
  uint2 r;
  r.x = *reinterpret_cast<unsigned int*>(&h0);
  r.y = *reinterpret_cast<unsigned int*>(&h1);
  return r;
}

// global-read granule pattern for the first sweep (window {0,1,11,12,13})
#define A1 (tid | (rr << 9))
// H-pass local->global 4-amp-granule map (local l0..l5=g0..g5, l6..l13=g13..g20)
#define GH(l4) (((l4) & 0xF) | (t << 4) | (((l4) >> 4) << 11))

// ---------------- L pass: tile = bits 0..13, t = bits 14..20 ----------------
// S1 {0,1,11,12,13} -> sigma2(swap 0<->7,1<->8) -> S2 {7..11} -> sigma3(swap
// 0<->3,1<->4) -> S3 {3..7} -> identity -> S4 {0..4}.
template<bool INIT>
__global__ __launch_bounds__(512, 4) void k_L(const float* __restrict__ x,
                                              const float* __restrict__ w,
                                              unsigned long long stp) {
  __shared__ __align__(16) float s[16384];
  float4* s4 = reinterpret_cast<float4*>(s);
  const int tid = threadIdx.x, lane = tid & 63;
  const int b = blockIdx.x >> 7, t = blockIdx.x & 127;
  float cv = 1.f, sv = 0.f;
  if (lane < NQ) sincosf(0.5f * w[lane], &sv, &cv);
  uint2* g2 = reinterpret_cast<uint2*>(stp) + ((size_t)b << 19) + ((size_t)t << 12);
  float v[32];
  float4* v4 = reinterpret_cast<float4*>(v);

  // ---- S1: window {0,1,11,12,13}: C(13,12),(12,11); RY 13(q7),12(q8) ----
  if (INIT) {
    // product state after x-RYs, pre-imaged through layer-1 chain C(20,19)..(14,13)
    float cx = 1.f, sx = 0.f;
    if (lane < NQ) sincosf(0.5f * x[b * NQ + lane], &sx, &cx);
    float Qp = 1.f;
#pragma unroll
    for (int i = 0; i < 9; ++i) {            // tid bit i -> g(2+i) -> qubit 18-i
      float cq = __shfl(cx, 18 - i), sq = __shfl(sx, 18 - i);
      Qp *= ((tid >> i) & 1) ? sq : cq;
    }
    float hfac[2];
#pragma unroll
    for (int bb = 0; bb < 2; ++bb) {         // g13 = bb, h = g[13..20]
      int h = (t << 1) | bb;
      int h0 = h ^ (h >> 1);                 // pre-image of high chain
      float p = 1.f;
#pragma unroll
      for (int j = 0; j < 8; ++j) {          // h0 bit j -> g(13+j) -> qubit 7-j
        float cq = __shfl(cx, 7 - j), sq = __shfl(sx, 7 - j);
        p *= ((h0 >> j) & 1) ? sq : cq;
      }
      hfac[bb] = p;
    }
    float c20 = __shfl(cx, 20), s20 = __shfl(sx, 20);
    float c19 = __shfl(cx, 19), s19 = __shfl(sx, 19);
    float c9  = __shfl(cx, 9),  s9  = __shfl(sx, 9);
    float c8  = __shfl(cx, 8),  s8  = __shfl(sx, 8);
    float w0t[4], w1t[4];
#pragma unroll
    for (int i = 0; i < 4; ++i) {
      w0t[i] = ((i & 1) ? s20 : c20) * ((i & 2) ? s19 : c19);  // amp bits 0,1
      w1t[i] = ((i & 1) ? s9  : c9 ) * ((i & 2) ? s8  : c8 );  // amp bits 11,12
    }
#pragma unroll
    for (int r = 0; r < 32; ++r)
      v[r] = hfac[(r >> 4) & 1] * w1t[(r >> 2) & 3] * w0t[r & 3] * Qp;
  } else {
#pragma unroll
    for (int rr = 0; rr < 8; ++rr) ld4(g2, A1, v + 4 * rr);
  }
  cnot32<4, 3>(v); cnot32<3, 2>(v);
  ry32<4>(v, SHC(7)); ry32<3>(v, SHC(8));
  {
    // write sigma2 layout: amp{2..10}<-tid: s2..s6<-t0..4, s0,s1<-t5,t6, s9,s10<-t7,t8
    const int pb = PH2(((tid & 31) << 2) | ((tid >> 5) & 3) | (((tid >> 7) & 3) << 9));
#pragma unroll
    for (int r = 0; r < 32; ++r)
      s[pb ^ PH2(((r & 3) << 7) | ((r >> 2) << 11))] = v[r];
  }
  __syncthreads();

  // ---- S2: window {7..11}: C(11,10),(10,9),(9,8),(8,7); RY 11..8 (q9..q12) ----
  {
    const int pb = PH2(((tid & 3) << 7) | (tid & 0x7C) | ((tid >> 7) << 12));
#pragma unroll
    for (int rr = 0; rr < 8; ++rr) v4[rr] = s4[(pb ^ PH2(rr << 9)) >> 2];
  }
  cnot32<4, 3>(v); cnot32<3, 2>(v); cnot32<2, 1>(v); cnot32<1, 0>(v);
  ry32<4>(v, SHC(9)); ry32<3>(v, SHC(10)); ry32<2>(v, SHC(11)); ry32<1>(v, SHC(12));
  __syncthreads();
  {
    // write sigma3 layout: s3,s4<-t0,t1; s2<-t2; s0,s1<-t3,t4; s5,s6<-t5,t6; s12,s13<-t7,t8
    const int pb = PH2(((tid >> 3) & 3) | (tid & 4) | ((tid & 3) << 3) |
                       (tid & 0x60) | ((tid >> 7) << 12));
#pragma unroll
    for (int r = 0; r < 32; ++r) s[pb ^ PH2(r << 7)] = v[r];
  }
  __syncthreads();

  // ---- S3: window {3..7}: C(7,6),(6,5),(5,4),(4,3); RY 7..4 (q13..q16) ----
  {
    const int pb = PH2(((tid & 3) << 3) | (tid & 4) | ((tid >> 3) << 8));
#pragma unroll
    for (int rr = 0; rr < 8; ++rr) v4[rr] = s4[(pb ^ PH2(rr << 5)) >> 2];
  }
  cnot32<4, 3>(v); cnot32<3, 2>(v); cnot32<2, 1>(v); cnot32<1, 0>(v);
  ry32<4>(v, SHC(13)); ry32<3>(v, SHC(14)); ry32<2>(v, SHC(15)); ry32<1>(v, SHC(16));
  __syncthreads();
  {
    // write identity layout
    const int pb = PH2((tid & 7) | ((tid >> 3) << 8));
#pragma unroll
    for (int r = 0; r < 32; ++r) s[pb ^ PH2(r << 3)] = v[r];
  }
  __syncthreads();

  // ---- S4: window {0..4}: C(3,2),(2,1),(1,0); RY 3,2,1 (q17,q18,q19); store ----
  {
    const int pb = PH2(tid << 5);
#pragma unroll
    for (int rr = 0; rr < 8; ++rr) v4[rr] = s4[(pb ^ PH2(rr << 2)) >> 2];
  }
  cnot32<3, 2>(v); cnot32<2, 1>(v); cnot32<1, 0>(v);
  ry32<3>(v, SHC(17)); ry32<2>(v, SHC(18)); ry32<1>(v, SHC(19));
  {
    uint4* g4o = reinterpret_cast<uint4*>(g2);
#pragma unroll
    for (int rr = 0; rr < 8; rr += 2) {
      uint2 lo = pk4(v + 4 * rr), hi = pk4(v + 4 * rr + 4);
      uint4 o; o.x = lo.x; o.y = lo.y; o.z = hi.x; o.w = hi.y;
      g4o[((rr | (tid << 3)) >> 1)] = o;
    }
  }
}

// ---------------- H pass: tile = bits {0..5,13..20}, t = bits 6..12 ----------------
// HS1 {l0,l1,l11,l12,l13} -> sigma2 -> HS2 {l7..l11} -> identity -> HS3 {l0,l1,l5,l6,l7}
__global__ __launch_bounds__(512, 4) void k_H(const float* __restrict__ w,
                                              unsigned long long stp) {
  __shared__ __align__(16) float s[16384];
  float4* s4 = reinterpret_cast<float4*>(s);
  const int tid = threadIdx.x, lane = tid & 63;
  const int b = blockIdx.x >> 7, t = blockIdx.x & 127;
  float cv = 1.f, sv = 0.f;
  if (lane < NQ) sincosf(0.5f * w[lane], &sv, &cv);
  uint2* gb = reinterpret_cast<uint2*>(stp) + ((size_t)b << 19);
  float v[32];
  float4* v4 = reinterpret_cast<float4*>(v);

  // ---- HS1: wrap C(l0,l13); RY l0(q20),l13(q0),l12(q1),l11(q2); chain C(l13,l12),(l12,l11) ----
#pragma unroll
  for (int rr = 0; rr < 8; ++rr) ld4(gb, GH(A1), v + 4 * rr);
  cnot32<0, 4>(v);
  ry32<0>(v, SHC(20)); ry32<4>(v, SHC(0)); ry32<3>(v, SHC(1)); ry32<2>(v, SHC(2));
  cnot32<4, 3>(v); cnot32<3, 2>(v);
  {
    const int pb = PH2(((tid & 31) << 2) | ((tid >> 5) & 3) | (((tid >> 7) & 3) << 9));
#pragma unroll
    for (int r = 0; r < 32; ++r)
      s[pb ^ PH2(((r & 3) << 7) | ((r >> 2) << 11))] = v[r];
  }
  __syncthreads();

  // ---- HS2: RY l10(q3),l9(q4),l8(q5),l7(q6); chain C(l11,l10),(l10,l9),(l9,l8),(l8,l7) ----
  {
    const int pb = PH2(((tid & 3) << 7) | (tid & 0x7C) | ((tid >> 7) << 12));
#pragma unroll
    for (int rr = 0; rr < 8; ++rr) v4[rr] = s4[(pb ^ PH2(rr << 9)) >> 2];
  }
  ry32<3>(v, SHC(3)); ry32<2>(v, SHC(4)); ry32<1>(v, SHC(5)); ry32<0>(v, SHC(6));
  cnot32<4, 3>(v); cnot32<3, 2>(v); cnot32<2, 1>(v); cnot32<1, 0>(v);
  __syncthreads();
  {
    // write identity layout
    const int pb = PH2((tid & 127) | ((tid >> 7) << 12));
#pragma unroll
    for (int r = 0; r < 32; ++r) s[pb ^ PH2(r << 7)] = v[r];
  }
  __syncthreads();

  // ---- HS3: window {l0,l1,l5,l6,l7}: chain C(l7,l6); store ----
  {
    const int pb = PH2(((tid & 7) << 2) | ((tid >> 3) << 8));
#pragma unroll
    for (int rr = 0; rr < 8; ++rr) v4[rr] = s4[(pb ^ PH2(rr << 5)) >> 2];
  }
  cnot32<4, 3>(v);
#pragma unroll
  for (int rr = 0; rr < 8; ++rr) {
    int l4 = (tid & 7) | (rr << 3) | ((tid >> 3) << 6);
    gb[GH(l4)] = pk4(v + 4 * rr);
  }
}

// ---------------- final H pass + measurement ----------------
__global__ __launch_bounds__(512, 4) void k_Hfin(const float* __restrict__ w,
                                                 unsigned long long stp,
                                                 float* __restrict__ partial) {
  __shared__ __align__(16) float s[16384];
  float4* s4 = reinterpret_cast<float4*>(s);
  const int tid = threadIdx.x, lane = tid & 63;
  const int b = blockIdx.x >> 7, t = blockIdx.x & 127;
  float cv = 1.f, sv = 0.f;
  if (lane < NQ) sincosf(0.5f * w[lane], &sv, &cv);
  const uint2* gb = reinterpret_cast<const uint2*>(stp) + ((size_t)b << 19);
  float v[32];
  float4* v4 = reinterpret_cast<float4*>(v);

  // ---- HS1f: wrap; RY l0,l13,l12,l11 ----
#pragma unroll
  for (int rr = 0; rr < 8; ++rr) ld4(gb, GH(A1), v + 4 * rr);
  cnot32<0, 4>(v);
  ry32<0>(v, SHC(20)); ry32<4>(v, SHC(0)); ry32<3>(v, SHC(1)); ry32<2>(v, SHC(2));
  {
    const int pb = PH2(((tid & 31) << 2) | ((tid >> 5) & 3) | (((tid >> 7) & 3) << 9));
#pragma unroll
    for (int r = 0; r < 32; ++r)
      s[pb ^ PH2(((r & 3) << 7) | ((r >> 2) << 11))] = v[r];
  }
  __syncthreads();

  // ---- HS2f: window {l7..l11}: RY l10(q3),l9(q4),l8(q5),l7(q6); measure ----
  {
    const int pb = PH2(((tid & 3) << 7) | (tid & 0x7C) | ((tid >> 7) << 12));
#pragma unroll
    for (int rr = 0; rr < 8; ++rr) v4[rr] = s4[(pb ^ PH2(rr << 9)) >> 2];
  }
  __syncthreads();   // all LDS reads done; s reused for reduction below
  ry32<3>(v, SHC(3)); ry32<2>(v, SHC(4)); ry32<1>(v, SHC(5)); ry32<0>(v, SHC(6));

  // reg bits: r0=l7=q6, r1=l8=q5, r2=l9=q4, r3=l10=q3, r4=l11=q2
  float S = 0, aq6 = 0, aq5 = 0, aq4 = 0, aq3 = 0, aq2 = 0;
#pragma unroll
  for (int r = 0; r < 32; ++r) {
    float p = v[r] * v[r];
    S += p;
    aq6 += (r & 1)  ? -p : p;
    aq5 += (r & 2)  ? -p : p;
    aq4 += (r & 4)  ? -p : p;
    aq3 += (r & 8)  ? -p : p;
    aq2 += (r & 16) ? -p : p;
  }
  float a21[21];
  a21[6] = aq6; a21[5] = aq5; a21[4] = aq4; a21[3] = aq3; a21[2] = aq2;
  a21[20] = (tid & 1)   ? -S : S;  // l0 = g0  -> q20
  a21[19] = (tid & 2)   ? -S : S;  // l1 = g1  -> q19
  a21[18] = (tid & 4)   ? -S : S;  // l2 = g2  -> q18
  a21[17] = (tid & 8)   ? -S : S;  // l3 = g3  -> q17
  a21[16] = (tid & 16)  ? -S : S;  // l4 = g4  -> q16
  a21[15] = (tid & 32)  ? -S : S;  // l5 = g5  -> q15
  a21[7]  = (tid & 64)  ? -S : S;  // l6 = g13 -> q7
  a21[1]  = (tid & 128) ? -S : S;  // l12 = g19 -> q1
  a21[0]  = (tid & 256) ? -S : S;  // l13 = g20 -> q0
  a21[14] = (t & 1)  ? -S : S;     // g6  -> q14
  a21[13] = (t & 2)  ? -S : S;
  a21[12] = (t & 4)  ? -S : S;
  a21[11] = (t & 8)  ? -S : S;
  a21[10] = (t & 16) ? -S : S;
  a21[9]  = (t & 32) ? -S : S;
  a21[8]  = (t & 64) ? -S : S;     // g12 -> q8

  const int wv = tid >> 6;
#pragma unroll
  for (int q = 0; q < 21; ++q) {
    float val = a21[q];
    val += __shfl_down(val, 32);
    val += __shfl_down(val, 16);
    val += __shfl_down(val, 8);
    val += __shfl_down(val, 4);
    val += __shfl_down(val, 2);
    val += __shfl_down(val, 1);
    if (lane == 0) s[q * 8 + wv] = val;
  }
  __syncthreads();
  if (tid < NQ) {
    float sum = 0.f;
#pragma unroll
    for (int k = 0; k < 8; ++k) sum += s[tid * 8 + k];
    partial[blockIdx.x * NQ + tid] = sum;
  }
}

// ---------------- deterministic final reduction (1 block x 672) ----------------
__global__ void k_red(const float* __restrict__ partial, float* __restrict__ out) {
  __shared__ float red[84][8];
  const int tid = threadIdx.x;
  const int pair = tid >> 3, k8 = tid & 7;
  if (pair < 84) {
    int b = pair / NQ, q = pair % NQ;
    float sum = 0.f;
#pragma unroll
    for (int i = 0; i < 16; ++i) sum += partial[(b * 128 + k8 * 16 + i) * NQ + q];
    red[pair][k8] = sum;
  }
  __syncthreads();
  if (tid < 84) {
    float sum = 0.f;
#pragma unroll
    for (int k = 0; k < 8; ++k) sum += red[tid][k];
    out[tid] = sum;     // tid == b*21 + q
  }
}

extern "C" void kernel_launch(void* const* d_in, const int* in_sizes, int n_in,
                              void* d_out, int out_size, void* d_ws, size_t ws_size,
                              hipStream_t stream) {
  const float* x = (const float*)d_in[0];   // (4,21) f32
  const float* w = (const float*)d_in[1];   // (3,21) f32
  float* out = (float*)d_out;               // (4,21) f32
  unsigned long long stp = (unsigned long long)d_ws;            // 4*2^21 fp16 = 16 MB
  float* partial = (float*)((char*)d_ws + (((size_t)4 << 21) * 2));  // 512*21 f32
  if (ws_size < ((size_t)4 << 21) * 2 + 512 * NQ * 4) return;

  dim3 grid(512), blk(512);
  k_L<true> <<<grid, blk, 0, stream>>>(x, w +  0, stp);
  k_H       <<<grid, blk, 0, stream>>>(w +  0, stp);
  k_L<false><<<grid, blk, 0, stream>>>(nullptr, w + 21, stp);
  k_H       <<<grid, blk, 0, stream>>>(w + 21, stp);
  k_L<false><<<grid, blk, 0, stream>>>(nullptr, w + 42, stp);
  k_Hfin    <<<grid, blk, 0, stream>>>(w + 42, stp, partial);
  k_red     <<<1, dim3(672), 0, stream>>>(partial, out);
}